// Round 22
// baseline (236.248 us; speedup 1.0000x reference)
//
#include <hip/hip_runtime.h>
#include <hip/hip_fp16.h>

constexpr int NUM_USER  = 100000;
constexpr int NUM_ITEM  = 50000;
constexpr int DIM       = 64;
constexpr int NUM_EDGES = 3200000;

constexpr int KPB   = 32;                             // keys per fine bucket
constexpr int NB_U  = (NUM_USER + KPB - 1) / KPB;     // 3125
constexpr int NB_I  = (NUM_ITEM + KPB - 1) / KPB;     // 1563
constexpr int CSH   = 14;                             // value-chunk shift
constexpr int NCH_I = 4;                              // item-value chunks
constexpr int NCH_U = 7;                              // user-value chunks
constexpr int BPB_U = NCH_I * KPB;                    // bins per user bucket = 128
constexpr int BPB_I = NCH_U * KPB;                    // bins per item bucket = 224
constexpr int CAP_U = 1280;                           // fine cap (mean 1024 + 8s)
constexpr int CAP_I = 2304;                           // fine cap (mean 2048 + 5.7s)
constexpr int PGRID = 256;                            // partition blocks
constexpr int CVTB  = 256;                            // fused cvt blocks (1/CU)
constexpr int NG    = 196;                            // coarse groups per direction
constexpr int GSH_U = 9;                              // 512 user keys / group
constexpr int GSH_I = 8;                              // 256 item keys / group
constexpr int FBG_U = 16;                             // fine buckets / user group
constexpr int FBG_I = 8;                              // fine buckets / item group
constexpr int GCAP  = 17152;                          // coarse cap (mean 16384 + 6s)

// ---------------------------------------------------------------------------
__device__ __forceinline__ __half2 u2h(unsigned u) {
  union { unsigned u; __half2 h; } v; v.u = u; return v.h;
}
__device__ __forceinline__ unsigned h2u(__half2 h) {
  union { __half2 h; unsigned u; } v; v.h = h; return v.u;
}
__device__ __forceinline__ float u_as_f(unsigned u) {
  union { unsigned u; float f; } v; v.u = u; return v.f;
}

__device__ __forceinline__ int detect64(const void* eu, const void* ei) {
  const int* a = (const int*)eu;
  const int* b = (const int*)ei;
  int any = 0;
#pragma unroll
  for (int i = 1; i < 64; i += 2) { any |= a[i]; any |= b[i]; }
  return any == 0;
}

__device__ __forceinline__ int idx_at(const void* p, int e, int is64) {
  return is64 ? ((const int*)p)[2 * e] : ((const int*)p)[e];
}

// cvt worker: f32 -> packed-f16 tables (nt loads + nt stores).
// user32: per user row = 32 dwords, dword c = f16 dims (2c, 2c+1).
// fused : per item row = 64 dwords; dword 2c = item f16, 2c+1 = agg f16.
__device__ __forceinline__ void cvt_body(int t0, int stride,
                                         const float* __restrict__ ue,
                                         unsigned* __restrict__ u32,
                                         const float* __restrict__ ie,
                                         unsigned* __restrict__ fused) {
  const int nu = NUM_USER * 32, ni = NUM_ITEM * 32;
  for (int t = t0; t < nu + ni; t += stride) {
    if (t < nu) {
      const unsigned long long raw =
          __builtin_nontemporal_load((const unsigned long long*)ue + t);
      const __half2 h = __floats2half2_rn(u_as_f((unsigned)raw),
                                          u_as_f((unsigned)(raw >> 32)));
      __builtin_nontemporal_store(h2u(h), &u32[t]);
    } else {
      const int s = t - nu;
      const unsigned long long raw =
          __builtin_nontemporal_load((const unsigned long long*)ie + s);
      const __half2 h = __floats2half2_rn(u_as_f((unsigned)raw),
                                          u_as_f((unsigned)(raw >> 32)));
      __builtin_nontemporal_store(h2u(h),
                                  &fused[(size_t)(s >> 5) * 64 + 2 * (s & 31)]);
    }
  }
}

// ---------------------------------------------------------------------------
// Pass A: coarse partition (196 groups/dir) + fused cvt (proven R16-R21).
// ---------------------------------------------------------------------------
__global__ void k_passA(const void* eu_p, const void* ei_p,
                        int* gccur_u, int* gccur_i,
                        unsigned* __restrict__ coarse_u,
                        unsigned* __restrict__ coarse_i,
                        const float* __restrict__ ue, unsigned* __restrict__ u32t,
                        const float* __restrict__ ie, unsigned* __restrict__ fusedt) {
  __shared__ int hu[NG], bu[NG];
  __shared__ int hi_[NG], bi_[NG];
  if (blockIdx.x >= PGRID) {
    cvt_body((blockIdx.x - PGRID) * blockDim.x + threadIdx.x,
             CVTB * blockDim.x, ue, u32t, ie, fusedt);
    return;
  }
  for (int t = threadIdx.x; t < NG; t += blockDim.x) { hu[t] = 0; hi_[t] = 0; }
  __syncthreads();
  const int is64 = detect64(eu_p, ei_p);
  const int ch = NUM_EDGES / PGRID;
  const int lo = blockIdx.x * ch, hiE = lo + ch;
  for (int e = lo + threadIdx.x; e < hiE; e += blockDim.x) {
    atomicAdd(&hu[idx_at(eu_p, e, is64) >> GSH_U], 1);
    atomicAdd(&hi_[idx_at(ei_p, e, is64) >> GSH_I], 1);
  }
  __syncthreads();
  for (int t = threadIdx.x; t < NG; t += blockDim.x) {
    const int h0 = hu[t];
    bu[t] = h0 ? atomicAdd(&gccur_u[t], h0) : 0;
    hu[t] = 0;
    const int h1 = hi_[t];
    bi_[t] = h1 ? atomicAdd(&gccur_i[t], h1) : 0;
    hi_[t] = 0;
  }
  __syncthreads();
  for (int e = lo + threadIdx.x; e < hiE; e += blockDim.x) {
    const int eu = idx_at(eu_p, e, is64);
    const int ei = idx_at(ei_p, e, is64);
    const int gu = eu >> GSH_U;
    const int pu = bu[gu] + atomicAdd(&hu[gu], 1);
    if (pu < GCAP)
      coarse_u[(size_t)gu * GCAP + pu] =
          ((unsigned)(eu & ((1 << GSH_U) - 1)) << 17) | (unsigned)ei;
    const int gi = ei >> GSH_I;
    const int pi = bi_[gi] + atomicAdd(&hi_[gi], 1);
    if (pi < GCAP)
      coarse_i[(size_t)gi * GCAP + pi] =
          ((unsigned)(ei & ((1 << GSH_I) - 1)) << 17) | (unsigned)eu;
  }
}

// ---------------------------------------------------------------------------
// Pass B (light): one block per coarse group; re-partition into 32-key fine
// buckets. Zero global atomics; exact counts. (Proven R17/R21.)
// ---------------------------------------------------------------------------
__global__ void k_passB(const unsigned* __restrict__ coarse_u,
                        const unsigned* __restrict__ coarse_i,
                        const int* __restrict__ gccur_u,
                        const int* __restrict__ gccur_i,
                        unsigned* __restrict__ pairs_u,
                        unsigned* __restrict__ pairs_i,
                        int* __restrict__ gcnt_u, int* __restrict__ gcnt_i) {
  __shared__ int h[FBG_U], cur[FBG_U];
  const bool isU = blockIdx.x < NG;
  const int g = isU ? blockIdx.x : blockIdx.x - NG;
  const unsigned* src = (isU ? coarse_u : coarse_i) + (size_t)g * GCAP;
  int n = isU ? gccur_u[g] : gccur_i[g];
  n = min(n, GCAP);
  const int FB = isU ? FBG_U : FBG_I;
  const int CAP = isU ? CAP_U : CAP_I;
  const int NBfin = isU ? NB_U : NB_I;
  unsigned* dst = isU ? pairs_u : pairs_i;
  int* gcnt = isU ? gcnt_u : gcnt_i;
  const int tid = threadIdx.x;

  if (tid < FB) h[tid] = 0;
  __syncthreads();
  for (int j = tid; j < n; j += blockDim.x)
    atomicAdd(&h[(src[j] >> 22) & (FB - 1)], 1);
  __syncthreads();
  if (tid < FB) {
    const int fbg = g * FB + tid;
    if (fbg < NBfin) gcnt[fbg] = min(h[tid], CAP);
    cur[tid] = 0;
  }
  __syncthreads();
  for (int j = tid; j < n; j += blockDim.x) {
    const unsigned p = src[j];
    const int fb = (p >> 22) & (FB - 1);
    const int pos = atomicAdd(&cur[fb], 1);
    if (pos < CAP)
      dst[(size_t)(g * FB + fb) * CAP + pos] = p & 0x3FFFFFu;
  }
}

// ---------------------------------------------------------------------------
// Aggregation, dir-I: 224 bins, single window, WIDE gather: 16 lanes x uint2
// per row (4 pairs per wave via lane quarters). Counts recomputed from LDS
// base/cur at the epilogue (no cnt registers).
// ---------------------------------------------------------------------------
__global__ __launch_bounds__(256, 8)
void k_agg_item(const unsigned* __restrict__ user32,
                const unsigned int* __restrict__ pairs,
                const int* __restrict__ gcnt,
                unsigned* __restrict__ fused) {
  constexpr int NBINS = BPB_I;
  __shared__ int sorted[CAP_I];                 // 9.2 KB
  __shared__ int hist[NBINS], base[NBINS], cur[NBINS];
  __shared__ int gsum[NCH_U];
  const int tid = threadIdx.x;
  const int lane = tid & 63;
  const int wid = tid >> 6;
  const int quarter = lane >> 4;
  const int k = lane & 15;
  const int bucket = blockIdx.x;
  const int lo = bucket * CAP_I;
  const int csz = min(gcnt[bucket], CAP_I);
  const uint2* user2 = (const uint2*)user32;    // row = 16 uint2

  unsigned sa[8], sb[8];
#pragma unroll
  for (int r = 0; r < 8; ++r) { sa[r] = 0u; sb[r] = 0u; }

  for (int t = tid; t < NBINS; t += 256) hist[t] = 0;
  __syncthreads();
  for (int j = tid; j < csz; j += 256) {
    const unsigned p = pairs[lo + j];
    atomicAdd(&hist[((p & 0x1FFFF) >> CSH) * KPB + (p >> 17)], 1);
  }
  __syncthreads();
  if (tid < NCH_U) {
    int g = 0;
    for (int q = 0; q < KPB; ++q) g += hist[tid * KPB + q];
    gsum[tid] = g;
  }
  __syncthreads();
  for (int t = tid; t < NBINS; t += 256) {
    const int ch = t >> 5;
    int b = 0;
    for (int q = 0; q < ch; ++q) b += gsum[q];
    for (int q = ch * KPB; q < t; ++q) b += hist[q];
    base[t] = b; cur[t] = b;
  }
  __syncthreads();
  for (int j = tid; j < csz; j += 256) {
    const unsigned p = pairs[lo + j];
    const int v = (int)(p & 0x1FFFF);
    const int slot = atomicAdd(&cur[(v >> CSH) * KPB + (p >> 17)], 1);
    sorted[slot] = v;
  }
  __syncthreads();
  for (int ch = 0; ch < NCH_U; ++ch) {
#pragma unroll
    for (int r = 0; r < 8; ++r) {
      const int bin = ch * KPB + wid * 8 + r;
      const int jlo = base[bin], jhi = cur[bin];
      for (int j = jlo; j < jhi; j += 8) {
        uint2 w[2];
#pragma unroll
        for (int q = 0; q < 2; ++q) {
          const int jj = j + 4 * q + quarter;
          w[q] = (jj < jhi) ? user2[(size_t)sorted[jj] * 16 + k]
                            : make_uint2(0u, 0u);
        }
#pragma unroll
        for (int q = 0; q < 2; ++q) {
          sa[r] = h2u(__hadd2(u2h(sa[r]), u2h(w[q].x)));
          sb[r] = h2u(__hadd2(u2h(sb[r]), u2h(w[q].y)));
        }
      }
    }
  }

  const int i0 = bucket * KPB;
#pragma unroll
  for (int r = 0; r < 8; ++r) {
    unsigned ta = sa[r], tb = sb[r];
    ta = h2u(__hadd2(u2h(ta), u2h((unsigned)__shfl_xor((int)ta, 16))));
    tb = h2u(__hadd2(u2h(tb), u2h((unsigned)__shfl_xor((int)tb, 16))));
    ta = h2u(__hadd2(u2h(ta), u2h((unsigned)__shfl_xor((int)ta, 32))));
    tb = h2u(__hadd2(u2h(tb), u2h((unsigned)__shfl_xor((int)tb, 32))));
    const int key = wid * 8 + r;
    const int item = i0 + key;
    if (quarter == 0 && item < NUM_ITEM) {
      int cnt = 0;
      for (int ch = 0; ch < NCH_U; ++ch)
        cnt += cur[ch * KPB + key] - base[ch * KPB + key];
      const float inv = 1.0f / fmaxf((float)cnt, 1.f);
      const __half2 ha = u2h(ta), hb = u2h(tb);
      // dims (4k,4k+1) -> agg slot dword 4k+1; dims (4k+2,4k+3) -> 4k+3
      fused[(size_t)item * 64 + 4 * k + 1] =
          h2u(__floats2half2_rn(__low2float(ha) * inv, __high2float(ha) * inv));
      fused[(size_t)item * 64 + 4 * k + 3] =
          h2u(__floats2half2_rn(__low2float(hb) * inv, __high2float(hb) * inv));
    }
  }
}

// ---------------------------------------------------------------------------
// Aggregation, dir-U: 128 bins; pairs staged in LDS (R21); WIDE gather:
// 16 lanes x uint4 per 256B fused row (4 pairs per wave). Epilogue float4.
// ---------------------------------------------------------------------------
__global__ __launch_bounds__(256, 8)
void k_agg_user(const unsigned* __restrict__ fused,
                const unsigned int* __restrict__ pairs,
                const int* __restrict__ gcnt,
                float* __restrict__ out0, float* __restrict__ out1) {
  constexpr int NBINS = BPB_U;
  __shared__ unsigned sv[CAP_U];                // 5.0 KB staged pairs
  __shared__ int sorted[CAP_U];                 // 5.0 KB
  __shared__ int hist[NBINS], base[NBINS], cur[NBINS];
  __shared__ int gsum[NCH_I];
  const int tid = threadIdx.x;
  const int lane = tid & 63;
  const int wid = tid >> 6;
  const int quarter = lane >> 4;
  const int k = lane & 15;
  const int bucket = blockIdx.x;
  const int lo = bucket * CAP_U;
  const int csz = min(gcnt[bucket], CAP_U);
  const uint4* fused4 = (const uint4*)fused;    // row = 16 uint4

  unsigned s0a[8], s0b[8], s1a[8], s1b[8];
#pragma unroll
  for (int r = 0; r < 8; ++r) { s0a[r] = 0u; s0b[r] = 0u; s1a[r] = 0u; s1b[r] = 0u; }

  for (int t = tid; t < NBINS; t += 256) hist[t] = 0;
  for (int j = tid; j < csz; j += 256) sv[j] = pairs[lo + j];
  __syncthreads();
  for (int j = tid; j < csz; j += 256) {
    const unsigned p = sv[j];
    atomicAdd(&hist[((p & 0x1FFFF) >> CSH) * KPB + (p >> 17)], 1);
  }
  __syncthreads();
  if (tid < NCH_I) {
    int g = 0;
    for (int q = 0; q < KPB; ++q) g += hist[tid * KPB + q];
    gsum[tid] = g;
  }
  __syncthreads();
  for (int t = tid; t < NBINS; t += 256) {
    const int ch = t >> 5;
    int b = 0;
    for (int q = 0; q < ch; ++q) b += gsum[q];
    for (int q = ch * KPB; q < t; ++q) b += hist[q];
    base[t] = b; cur[t] = b;
  }
  __syncthreads();
  for (int j = tid; j < csz; j += 256) {
    const unsigned p = sv[j];
    const int v = (int)(p & 0x1FFFF);
    const int slot = atomicAdd(&cur[(v >> CSH) * KPB + (p >> 17)], 1);
    sorted[slot] = v;
  }
  __syncthreads();
  for (int ch = 0; ch < NCH_I; ++ch) {
#pragma unroll
    for (int r = 0; r < 8; ++r) {
      const int bin = ch * KPB + wid * 8 + r;
      const int jlo = base[bin], jhi = cur[bin];
      for (int j = jlo; j < jhi; j += 8) {
        uint4 w[2];
#pragma unroll
        for (int q = 0; q < 2; ++q) {
          const int jj = j + 4 * q + quarter;
          w[q] = (jj < jhi) ? fused4[(size_t)sorted[jj] * 16 + k]
                            : make_uint4(0u, 0u, 0u, 0u);
        }
#pragma unroll
        for (int q = 0; q < 2; ++q) {
          s0a[r] = h2u(__hadd2(u2h(s0a[r]), u2h(w[q].x)));
          s1a[r] = h2u(__hadd2(u2h(s1a[r]), u2h(w[q].y)));
          s0b[r] = h2u(__hadd2(u2h(s0b[r]), u2h(w[q].z)));
          s1b[r] = h2u(__hadd2(u2h(s1b[r]), u2h(w[q].w)));
        }
      }
    }
  }

  const int u0 = bucket * KPB;
#pragma unroll
  for (int r = 0; r < 8; ++r) {
    unsigned t0a = s0a[r], t0b = s0b[r], t1a = s1a[r], t1b = s1b[r];
    t0a = h2u(__hadd2(u2h(t0a), u2h((unsigned)__shfl_xor((int)t0a, 16))));
    t0b = h2u(__hadd2(u2h(t0b), u2h((unsigned)__shfl_xor((int)t0b, 16))));
    t1a = h2u(__hadd2(u2h(t1a), u2h((unsigned)__shfl_xor((int)t1a, 16))));
    t1b = h2u(__hadd2(u2h(t1b), u2h((unsigned)__shfl_xor((int)t1b, 16))));
    t0a = h2u(__hadd2(u2h(t0a), u2h((unsigned)__shfl_xor((int)t0a, 32))));
    t0b = h2u(__hadd2(u2h(t0b), u2h((unsigned)__shfl_xor((int)t0b, 32))));
    t1a = h2u(__hadd2(u2h(t1a), u2h((unsigned)__shfl_xor((int)t1a, 32))));
    t1b = h2u(__hadd2(u2h(t1b), u2h((unsigned)__shfl_xor((int)t1b, 32))));
    const int key = wid * 8 + r;
    const int u = u0 + key;
    if (quarter == 0 && u < NUM_USER) {
      int cnt = 0;
      for (int ch = 0; ch < NCH_I; ++ch)
        cnt += cur[ch * KPB + key] - base[ch * KPB + key];
      const float inv = 1.0f / fmaxf((float)cnt, 1.f);
      const __half2 h0a = u2h(t0a), h0b = u2h(t0b);
      const __half2 h1a = u2h(t1a), h1b = u2h(t1b);
      ((float4*)out0)[(size_t)u * 16 + k] =
          make_float4(__low2float(h0a) * inv, __high2float(h0a) * inv,
                      __low2float(h0b) * inv, __high2float(h0b) * inv);
      ((float4*)out1)[(size_t)u * 16 + k] =
          make_float4(__low2float(h1a) * inv, __high2float(h1a) * inv,
                      __low2float(h1b) * inv, __high2float(h1b) * inv);
    }
  }
}

// ---------------------------------------------------------------------------
// Tier-1: one-level partition + cvt (proven R16).
// ---------------------------------------------------------------------------
__global__ void k_part2cvt(const void* eu_p, const void* ei_p,
                           int* gcur_i, unsigned int* __restrict__ pairs_i,
                           int* gcur_u, unsigned int* __restrict__ pairs_u,
                           const float* __restrict__ ue, unsigned* __restrict__ u32t,
                           const float* __restrict__ ie, unsigned* __restrict__ fusedt) {
  __shared__ int hist_u[NB_U], base_u[NB_U];
  __shared__ int hist_i[NB_I], base_i[NB_I];
  if (blockIdx.x >= PGRID) {
    cvt_body((blockIdx.x - PGRID) * blockDim.x + threadIdx.x,
             CVTB * blockDim.x, ue, u32t, ie, fusedt);
    return;
  }
  for (int t = threadIdx.x; t < NB_U; t += blockDim.x) hist_u[t] = 0;
  for (int t = threadIdx.x; t < NB_I; t += blockDim.x) hist_i[t] = 0;
  __syncthreads();
  const int is64 = detect64(eu_p, ei_p);
  const int ch = NUM_EDGES / PGRID;
  const int lo = blockIdx.x * ch, hiE = lo + ch;
  for (int e = lo + threadIdx.x; e < hiE; e += blockDim.x) {
    atomicAdd(&hist_u[idx_at(eu_p, e, is64) >> 5], 1);
    atomicAdd(&hist_i[idx_at(ei_p, e, is64) >> 5], 1);
  }
  __syncthreads();
  for (int t = threadIdx.x; t < NB_U; t += blockDim.x) {
    const int h = hist_u[t];
    base_u[t] = h ? t * CAP_U + atomicAdd(&gcur_u[t], h) : 0;
    hist_u[t] = 0;
  }
  for (int t = threadIdx.x; t < NB_I; t += blockDim.x) {
    const int h = hist_i[t];
    base_i[t] = h ? t * CAP_I + atomicAdd(&gcur_i[t], h) : 0;
    hist_i[t] = 0;
  }
  __syncthreads();
  for (int e = lo + threadIdx.x; e < hiE; e += blockDim.x) {
    const int eu = idx_at(eu_p, e, is64);
    const int ei = idx_at(ei_p, e, is64);
    const int bi = ei >> 5;
    const int pi = base_i[bi] + atomicAdd(&hist_i[bi], 1);
    if (pi < (bi + 1) * CAP_I)
      pairs_i[pi] = ((unsigned)(ei & 31) << 17) | (unsigned)eu;
    const int bu = eu >> 5;
    const int pu = base_u[bu] + atomicAdd(&hist_u[bu], 1);
    if (pu < (bu + 1) * CAP_U)
      pairs_u[pu] = ((unsigned)(eu & 31) << 17) | (unsigned)ei;
  }
}

// ---------------------------------------------------------------------------
// Round-0 atomic fallback (tiny ws).
// ---------------------------------------------------------------------------
__global__ void k_scatter1(const float* __restrict__ user_emb,
                           const float* __restrict__ item_emb,
                           const void* eu_p, const void* ei_p,
                           float* out0, float* item_sum,
                           float* cnt_user, float* cnt_item) {
  const int is64 = detect64(eu_p, ei_p);
  const int lane = threadIdx.x & (DIM - 1);
  const int sub  = threadIdx.x >> 6;
  const int epb  = blockDim.x >> 6;
  for (int e = blockIdx.x * epb + sub; e < NUM_EDGES; e += gridDim.x * epb) {
    const int eu = idx_at(eu_p, e, is64);
    const int ei = idx_at(ei_p, e, is64);
    atomicAdd(&out0[eu * DIM + lane], item_emb[ei * DIM + lane]);
    atomicAdd(&item_sum[ei * DIM + lane], user_emb[eu * DIM + lane]);
    if (lane == 0) {
      atomicAdd(&cnt_user[eu], 1.0f);
      atomicAdd(&cnt_item[ei], 1.0f);
    }
  }
}

__global__ void k_div_item(float* item_sum, const float* __restrict__ cnt_item) {
  const int n = NUM_ITEM * DIM;
  for (int t = blockIdx.x * blockDim.x + threadIdx.x; t < n;
       t += gridDim.x * blockDim.x)
    item_sum[t] /= fmaxf(cnt_item[t >> 6], 1.0f);
}

__global__ void k_scatter2(const float* __restrict__ item_agg,
                           const void* eu_p, const void* ei_p, float* out1) {
  const int is64 = detect64(eu_p, ei_p);
  const int lane = threadIdx.x & (DIM - 1);
  const int sub  = threadIdx.x >> 6;
  const int epb  = blockDim.x >> 6;
  for (int e = blockIdx.x * epb + sub; e < NUM_EDGES; e += gridDim.x * epb) {
    const int eu = idx_at(eu_p, e, is64);
    const int ei = idx_at(ei_p, e, is64);
    atomicAdd(&out1[eu * DIM + lane], item_agg[ei * DIM + lane]);
  }
}

__global__ void k_finalize(float* out0, float* out1,
                           const float* __restrict__ cnt_user) {
  const int n = NUM_USER * DIM;
  for (int t = blockIdx.x * blockDim.x + threadIdx.x; t < n;
       t += gridDim.x * blockDim.x) {
    const float c = fmaxf(cnt_user[t >> 6], 1.0f);
    out0[t] /= c;
    out1[t] /= c;
  }
}

// ---------------------------------------------------------------------------
extern "C" void kernel_launch(void* const* d_in, const int* in_sizes, int n_in,
                              void* d_out, int out_size, void* d_ws, size_t ws_size,
                              hipStream_t stream) {
  const float* user_emb = (const float*)d_in[0];
  const float* item_emb = (const float*)d_in[1];
  const void*  eu_p     = d_in[2];
  const void*  ei_p     = d_in[3];

  float* out0 = (float*)d_out;
  float* out1 = out0 + (size_t)NUM_USER * DIM;

  int* wsi = (int*)d_ws;
  float* wsf = (float*)d_ws;

  // --- Tier 0: two-level partition layout (u32 units), ~82.9 MB (proven R17/R21) ---
  const size_t t0_coarse_u = 0;
  const size_t t0_coarse_i = t0_coarse_u + (size_t)NG * GCAP;
  const size_t t0_pairs_u  = t0_coarse_i + (size_t)NG * GCAP;
  const size_t t0_pairs_i  = t0_pairs_u + (size_t)NB_U * CAP_U;
  const size_t t0_user32   = t0_pairs_i + (size_t)NB_I * CAP_I;
  const size_t t0_fused    = t0_user32 + (size_t)NUM_USER * 32;
  const size_t t0_gccur    = t0_fused + (size_t)NUM_ITEM * 64;
  const size_t t0_gcnt_u   = t0_gccur + 2 * NG;
  const size_t t0_gcnt_i   = t0_gcnt_u + NB_U;
  const size_t need_t0     = (t0_gcnt_i + NB_I) * 4;

  // --- Tier 1: one-level static layout, 56.0 MB (proven R13-R16) ---
  const size_t s_pairs_u = 0;
  const size_t s_pairs_i = s_pairs_u + (size_t)NB_U * CAP_U;
  const size_t s_user32  = s_pairs_i + (size_t)NB_I * CAP_I;
  const size_t s_fused   = s_user32 + (size_t)NUM_USER * 32;
  const size_t s_gcur_u  = s_fused + (size_t)NUM_ITEM * 64;
  const size_t s_gcur_i  = s_gcur_u + NB_U;
  const size_t need_t1   = (s_gcur_i + NB_I) * 4;

  if (ws_size >= need_t0) {
    unsigned* coarse_u = (unsigned*)(wsi + t0_coarse_u);
    unsigned* coarse_i = (unsigned*)(wsi + t0_coarse_i);
    unsigned* pairs_u  = (unsigned*)(wsi + t0_pairs_u);
    unsigned* pairs_i  = (unsigned*)(wsi + t0_pairs_i);
    unsigned* user32   = (unsigned*)(wsi + t0_user32);
    unsigned* fused    = (unsigned*)(wsi + t0_fused);
    int* gccur_u = wsi + t0_gccur;
    int* gccur_i = gccur_u + NG;
    int* gcnt_u  = wsi + t0_gcnt_u;
    int* gcnt_i  = wsi + t0_gcnt_i;

    hipMemsetAsync(gccur_u, 0, (size_t)(2 * NG) * 4, stream);
    k_passA<<<PGRID + CVTB, 1024, 0, stream>>>(eu_p, ei_p, gccur_u, gccur_i,
                                               coarse_u, coarse_i,
                                               user_emb, user32, item_emb, fused);
    k_passB<<<2 * NG, 1024, 0, stream>>>(coarse_u, coarse_i, gccur_u, gccur_i,
                                         pairs_u, pairs_i, gcnt_u, gcnt_i);
    k_agg_item<<<NB_I, 256, 0, stream>>>(user32, pairs_i, gcnt_i, fused);
    k_agg_user<<<NB_U, 256, 0, stream>>>(fused, pairs_u, gcnt_u, out0, out1);
  } else if (ws_size >= need_t1) {
    unsigned* pairs_u = (unsigned*)(wsi + s_pairs_u);
    unsigned* pairs_i = (unsigned*)(wsi + s_pairs_i);
    unsigned* user32  = (unsigned*)(wsi + s_user32);
    unsigned* fused   = (unsigned*)(wsi + s_fused);
    int* gcur_u = wsi + s_gcur_u;
    int* gcur_i = wsi + s_gcur_i;

    hipMemsetAsync(gcur_u, 0, (size_t)(NB_U + NB_I) * 4, stream);
    k_part2cvt<<<PGRID + CVTB, 1024, 0, stream>>>(eu_p, ei_p, gcur_i, pairs_i,
                                                  gcur_u, pairs_u,
                                                  user_emb, user32,
                                                  item_emb, fused);
    k_agg_item<<<NB_I, 256, 0, stream>>>(user32, pairs_i, gcur_i, fused);
    k_agg_user<<<NB_U, 256, 0, stream>>>(fused, pairs_u, gcur_u, out0, out1);
  } else {
    float* item_sum = wsf;
    float* cnt_user = wsf + (size_t)NUM_ITEM * DIM;
    float* cnt_item = cnt_user + NUM_USER;
    const size_t used = ((size_t)NUM_ITEM * DIM + NUM_USER + NUM_ITEM) * 4;

    hipMemsetAsync(d_out, 0, (size_t)out_size * sizeof(float), stream);
    hipMemsetAsync(d_ws, 0, used, stream);
    k_scatter1<<<4096, 256, 0, stream>>>(user_emb, item_emb, eu_p, ei_p,
                                         out0, item_sum, cnt_user, cnt_item);
    k_div_item<<<2048, 256, 0, stream>>>(item_sum, cnt_item);
    k_scatter2<<<4096, 256, 0, stream>>>(item_sum, eu_p, ei_p, out1);
    k_finalize<<<2048, 256, 0, stream>>>(out0, out1, cnt_user);
  }
}

// Round 23
// 223.430 us; speedup vs baseline: 1.0574x; 1.0574x over previous
//
#include <hip/hip_runtime.h>
#include <hip/hip_fp16.h>

constexpr int NUM_USER  = 100000;
constexpr int NUM_ITEM  = 50000;
constexpr int DIM       = 64;
constexpr int NUM_EDGES = 3200000;

constexpr int KPB   = 32;                             // keys per fine bucket
constexpr int NB_U  = (NUM_USER + KPB - 1) / KPB;     // 3125
constexpr int NB_I  = (NUM_ITEM + KPB - 1) / KPB;     // 1563
constexpr int CSH   = 14;                             // value-chunk shift
constexpr int NCH_I = 4;                              // item-value chunks
constexpr int NCH_U = 7;                              // user-value chunks
constexpr int BPB_U = NCH_I * KPB;                    // bins per user bucket = 128
constexpr int BPB_I = NCH_U * KPB;                    // bins per item bucket = 224
constexpr int CAP_U = 1280;                           // fine cap (mean 1024 + 8s)
constexpr int CAP_I = 2304;                           // fine cap (mean 2048 + 5.7s)
constexpr int PGRID = 256;                            // partition blocks
constexpr int CVTB  = 256;                            // fused cvt blocks (1/CU)
constexpr int NG    = 196;                            // coarse groups per direction
constexpr int GSH_U = 9;                              // 512 user keys / group
constexpr int GSH_I = 8;                              // 256 item keys / group
constexpr int FBG_U = 16;                             // fine buckets / user group
constexpr int FBG_I = 8;                              // fine buckets / item group
constexpr int GCAP  = 17152;                          // coarse cap (mean 16384 + 6s)

// ---------------------------------------------------------------------------
__device__ __forceinline__ __half2 u2h(unsigned u) {
  union { unsigned u; __half2 h; } v; v.u = u; return v.h;
}
__device__ __forceinline__ unsigned h2u(__half2 h) {
  union { __half2 h; unsigned u; } v; v.h = h; return v.u;
}
__device__ __forceinline__ float u_as_f(unsigned u) {
  union { unsigned u; float f; } v; v.u = u; return v.f;
}

__device__ __forceinline__ int detect64(const void* eu, const void* ei) {
  const int* a = (const int*)eu;
  const int* b = (const int*)ei;
  int any = 0;
#pragma unroll
  for (int i = 1; i < 64; i += 2) { any |= a[i]; any |= b[i]; }
  return any == 0;
}

__device__ __forceinline__ int idx_at(const void* p, int e, int is64) {
  return is64 ? ((const int*)p)[2 * e] : ((const int*)p)[e];
}

// cvt worker: f32 -> packed-f16 tables (nt loads + nt stores).
// user32: per user row = 32 dwords, dword c = f16 dims (2c, 2c+1).
// fused : per item row = 64 dwords; dword 2c = item f16, 2c+1 = agg f16.
__device__ __forceinline__ void cvt_body(int t0, int stride,
                                         const float* __restrict__ ue,
                                         unsigned* __restrict__ u32,
                                         const float* __restrict__ ie,
                                         unsigned* __restrict__ fused) {
  const int nu = NUM_USER * 32, ni = NUM_ITEM * 32;
  for (int t = t0; t < nu + ni; t += stride) {
    if (t < nu) {
      const unsigned long long raw =
          __builtin_nontemporal_load((const unsigned long long*)ue + t);
      const __half2 h = __floats2half2_rn(u_as_f((unsigned)raw),
                                          u_as_f((unsigned)(raw >> 32)));
      __builtin_nontemporal_store(h2u(h), &u32[t]);
    } else {
      const int s = t - nu;
      const unsigned long long raw =
          __builtin_nontemporal_load((const unsigned long long*)ie + s);
      const __half2 h = __floats2half2_rn(u_as_f((unsigned)raw),
                                          u_as_f((unsigned)(raw >> 32)));
      __builtin_nontemporal_store(h2u(h),
                                  &fused[(size_t)(s >> 5) * 64 + 2 * (s & 31)]);
    }
  }
}

// ---------------------------------------------------------------------------
// Pass A: coarse partition (196 groups/dir) + fused cvt (proven R16-R21).
// coarse pair: (key_local << 17) | value.
// ---------------------------------------------------------------------------
__global__ void k_passA(const void* eu_p, const void* ei_p,
                        int* gccur_u, int* gccur_i,
                        unsigned* __restrict__ coarse_u,
                        unsigned* __restrict__ coarse_i,
                        const float* __restrict__ ue, unsigned* __restrict__ u32t,
                        const float* __restrict__ ie, unsigned* __restrict__ fusedt) {
  __shared__ int hu[NG], bu[NG];
  __shared__ int hi_[NG], bi_[NG];
  if (blockIdx.x >= PGRID) {
    cvt_body((blockIdx.x - PGRID) * blockDim.x + threadIdx.x,
             CVTB * blockDim.x, ue, u32t, ie, fusedt);
    return;
  }
  for (int t = threadIdx.x; t < NG; t += blockDim.x) { hu[t] = 0; hi_[t] = 0; }
  __syncthreads();
  const int is64 = detect64(eu_p, ei_p);
  const int ch = NUM_EDGES / PGRID;
  const int lo = blockIdx.x * ch, hiE = lo + ch;
  for (int e = lo + threadIdx.x; e < hiE; e += blockDim.x) {
    atomicAdd(&hu[idx_at(eu_p, e, is64) >> GSH_U], 1);
    atomicAdd(&hi_[idx_at(ei_p, e, is64) >> GSH_I], 1);
  }
  __syncthreads();
  for (int t = threadIdx.x; t < NG; t += blockDim.x) {
    const int h0 = hu[t];
    bu[t] = h0 ? atomicAdd(&gccur_u[t], h0) : 0;
    hu[t] = 0;
    const int h1 = hi_[t];
    bi_[t] = h1 ? atomicAdd(&gccur_i[t], h1) : 0;
    hi_[t] = 0;
  }
  __syncthreads();
  for (int e = lo + threadIdx.x; e < hiE; e += blockDim.x) {
    const int eu = idx_at(eu_p, e, is64);
    const int ei = idx_at(ei_p, e, is64);
    const int gu = eu >> GSH_U;
    const int pu = bu[gu] + atomicAdd(&hu[gu], 1);
    if (pu < GCAP)
      coarse_u[(size_t)gu * GCAP + pu] =
          ((unsigned)(eu & ((1 << GSH_U) - 1)) << 17) | (unsigned)ei;
    const int gi = ei >> GSH_I;
    const int pi = bi_[gi] + atomicAdd(&hi_[gi], 1);
    if (pi < GCAP)
      coarse_i[(size_t)gi * GCAP + pi] =
          ((unsigned)(ei & ((1 << GSH_I) - 1)) << 17) | (unsigned)eu;
  }
}

// ---------------------------------------------------------------------------
// Pass B (light): one block per coarse group; re-partition into 32-key fine
// buckets. Block owns the whole group -> zero global atomics, sequential
// per-bucket write runs, exact counts emitted. Final pair = p & 0x3FFFFF.
// ---------------------------------------------------------------------------
__global__ void k_passB(const unsigned* __restrict__ coarse_u,
                        const unsigned* __restrict__ coarse_i,
                        const int* __restrict__ gccur_u,
                        const int* __restrict__ gccur_i,
                        unsigned* __restrict__ pairs_u,
                        unsigned* __restrict__ pairs_i,
                        int* __restrict__ gcnt_u, int* __restrict__ gcnt_i) {
  __shared__ int h[FBG_U], cur[FBG_U];
  const bool isU = blockIdx.x < NG;
  const int g = isU ? blockIdx.x : blockIdx.x - NG;
  const unsigned* src = (isU ? coarse_u : coarse_i) + (size_t)g * GCAP;
  int n = isU ? gccur_u[g] : gccur_i[g];
  n = min(n, GCAP);
  const int FB = isU ? FBG_U : FBG_I;
  const int CAP = isU ? CAP_U : CAP_I;
  const int NBfin = isU ? NB_U : NB_I;
  unsigned* dst = isU ? pairs_u : pairs_i;
  int* gcnt = isU ? gcnt_u : gcnt_i;
  const int tid = threadIdx.x;

  if (tid < FB) h[tid] = 0;
  __syncthreads();
  for (int j = tid; j < n; j += blockDim.x)
    atomicAdd(&h[(src[j] >> 22) & (FB - 1)], 1);
  __syncthreads();
  if (tid < FB) {
    const int fbg = g * FB + tid;
    if (fbg < NBfin) gcnt[fbg] = min(h[tid], CAP);
    cur[tid] = 0;
  }
  __syncthreads();
  for (int j = tid; j < n; j += blockDim.x) {
    const unsigned p = src[j];
    const int fb = (p >> 22) & (FB - 1);
    const int pos = atomicAdd(&cur[fb], 1);
    if (pos < CAP)
      dst[(size_t)(g * FB + fb) * CAP + pos] = p & 0x3FFFFFu;
  }
}

// ---------------------------------------------------------------------------
// Aggregation, dir-I: one block per 32-key item region. Binned by
// (user-chunk, key): 7*32 = 224 bins, chunk = value >> 14 -> chunk-major
// gathers stay XCD-L2 resident. Single window (region <= CAP_I).
// Packed-f16 register accumulate, 2 pairs/wave, 4-wide ILP. (Proven R17/R21.)
// ---------------------------------------------------------------------------
__global__ __launch_bounds__(256, 8)
void k_agg_item(const unsigned* __restrict__ user32,
                const unsigned int* __restrict__ pairs,
                const int* __restrict__ gcnt,
                unsigned* __restrict__ fused) {
  constexpr int NBINS = BPB_I;
  __shared__ int sorted[CAP_I];                 // 9.2 KB (region fits)
  __shared__ int hist[NBINS], base[NBINS], cur[NBINS];
  __shared__ int gsum[NCH_U];
  const int tid = threadIdx.x;
  const int lane = tid & 63;
  const int wid = tid >> 6;
  const int half = lane >> 5;
  const int c = lane & 31;
  const int bucket = blockIdx.x;
  const int lo = bucket * CAP_I;
  const int csz = min(gcnt[bucket], CAP_I);

  unsigned s[8]; int cnt[8];
#pragma unroll
  for (int r = 0; r < 8; ++r) { s[r] = 0u; cnt[r] = 0; }

  for (int t = tid; t < NBINS; t += 256) hist[t] = 0;
  __syncthreads();
  for (int j = tid; j < csz; j += 256) {
    const unsigned p = pairs[lo + j];
    atomicAdd(&hist[((p & 0x1FFFF) >> CSH) * KPB + (p >> 17)], 1);
  }
  __syncthreads();
  if (tid < NCH_U) {
    int g = 0;
    for (int q = 0; q < KPB; ++q) g += hist[tid * KPB + q];
    gsum[tid] = g;
  }
  __syncthreads();
  for (int t = tid; t < NBINS; t += 256) {
    const int ch = t >> 5;
    int b = 0;
    for (int q = 0; q < ch; ++q) b += gsum[q];
    for (int q = ch * KPB; q < t; ++q) b += hist[q];
    base[t] = b; cur[t] = b;
  }
  __syncthreads();
  for (int j = tid; j < csz; j += 256) {
    const unsigned p = pairs[lo + j];
    const int v = (int)(p & 0x1FFFF);
    const int slot = atomicAdd(&cur[(v >> CSH) * KPB + (p >> 17)], 1);
    sorted[slot] = v;
  }
  __syncthreads();
  for (int ch = 0; ch < NCH_U; ++ch) {
#pragma unroll
    for (int r = 0; r < 8; ++r) {
      const int bin = ch * KPB + wid * 8 + r;
      const int jlo = base[bin], jhi = cur[bin];
      cnt[r] += jhi - jlo;
      for (int j = jlo; j < jhi; j += 8) {
        unsigned w[4];
#pragma unroll
        for (int q = 0; q < 4; ++q) {
          const int jj = j + 2 * q + half;
          w[q] = (jj < jhi) ? user32[(size_t)sorted[jj] * 32 + c] : 0u;
        }
#pragma unroll
        for (int q = 0; q < 4; ++q)
          s[r] = h2u(__hadd2(u2h(s[r]), u2h(w[q])));
      }
    }
  }

  const int i0 = bucket * KPB;
#pragma unroll
  for (int r = 0; r < 8; ++r) {
    const unsigned o = (unsigned)__shfl_xor((int)s[r], 32);
    const __half2 tot = __hadd2(u2h(s[r]), u2h(o));
    const int item = i0 + wid * 8 + r;
    if (half == 0 && item < NUM_ITEM) {
      const float inv = 1.0f / fmaxf((float)cnt[r], 1.f);
      fused[(size_t)item * 64 + 2 * c + 1] =
          h2u(__floats2half2_rn(__low2float(tot) * inv, __high2float(tot) * inv));
    }
  }
}

// ---------------------------------------------------------------------------
// Aggregation, dir-U: one block per 32-key user region; 4*32 = 128 bins.
// Pairs staged into LDS once (coalesced); hist + scatter run from LDS.
// Lane loads uint2 (item dword + agg dword) per pair in the gather.
// (Proven R21 — best measured configuration, 224.05 us total.)
// ---------------------------------------------------------------------------
__global__ __launch_bounds__(256, 8)
void k_agg_user(const unsigned* __restrict__ fused,
                const unsigned int* __restrict__ pairs,
                const int* __restrict__ gcnt,
                float* __restrict__ out0, float* __restrict__ out1) {
  constexpr int NBINS = BPB_U;
  __shared__ unsigned sv[CAP_U];                // 5.0 KB staged pairs
  __shared__ int sorted[CAP_U];                 // 5.0 KB
  __shared__ int hist[NBINS], base[NBINS], cur[NBINS];
  __shared__ int gsum[NCH_I];
  const int tid = threadIdx.x;
  const int lane = tid & 63;
  const int wid = tid >> 6;
  const int half = lane >> 5;
  const int c = lane & 31;
  const int bucket = blockIdx.x;
  const int lo = bucket * CAP_U;
  const int csz = min(gcnt[bucket], CAP_U);
  const uint2* fused2 = (const uint2*)fused;

  unsigned s0[8], s1[8]; int cnt[8];
#pragma unroll
  for (int r = 0; r < 8; ++r) { s0[r] = 0u; s1[r] = 0u; cnt[r] = 0; }

  for (int t = tid; t < NBINS; t += 256) hist[t] = 0;
  for (int j = tid; j < csz; j += 256) sv[j] = pairs[lo + j];
  __syncthreads();
  for (int j = tid; j < csz; j += 256) {
    const unsigned p = sv[j];
    atomicAdd(&hist[((p & 0x1FFFF) >> CSH) * KPB + (p >> 17)], 1);
  }
  __syncthreads();
  if (tid < NCH_I) {
    int g = 0;
    for (int q = 0; q < KPB; ++q) g += hist[tid * KPB + q];
    gsum[tid] = g;
  }
  __syncthreads();
  for (int t = tid; t < NBINS; t += 256) {
    const int ch = t >> 5;
    int b = 0;
    for (int q = 0; q < ch; ++q) b += gsum[q];
    for (int q = ch * KPB; q < t; ++q) b += hist[q];
    base[t] = b; cur[t] = b;
  }
  __syncthreads();
  for (int j = tid; j < csz; j += 256) {
    const unsigned p = sv[j];
    const int v = (int)(p & 0x1FFFF);
    const int slot = atomicAdd(&cur[(v >> CSH) * KPB + (p >> 17)], 1);
    sorted[slot] = v;
  }
  __syncthreads();
  for (int ch = 0; ch < NCH_I; ++ch) {
#pragma unroll
    for (int r = 0; r < 8; ++r) {
      const int bin = ch * KPB + wid * 8 + r;
      const int jlo = base[bin], jhi = cur[bin];
      cnt[r] += jhi - jlo;
      for (int j = jlo; j < jhi; j += 8) {
        uint2 w[4];
#pragma unroll
        for (int q = 0; q < 4; ++q) {
          const int jj = j + 2 * q + half;
          w[q] = (jj < jhi) ? fused2[(size_t)sorted[jj] * 32 + c]
                            : make_uint2(0u, 0u);
        }
#pragma unroll
        for (int q = 0; q < 4; ++q) {
          s0[r] = h2u(__hadd2(u2h(s0[r]), u2h(w[q].x)));
          s1[r] = h2u(__hadd2(u2h(s1[r]), u2h(w[q].y)));
        }
      }
    }
  }

  const int u0 = bucket * KPB;
#pragma unroll
  for (int r = 0; r < 8; ++r) {
    const unsigned o0 = (unsigned)__shfl_xor((int)s0[r], 32);
    const unsigned o1 = (unsigned)__shfl_xor((int)s1[r], 32);
    const __half2 t0 = __hadd2(u2h(s0[r]), u2h(o0));
    const __half2 t1 = __hadd2(u2h(s1[r]), u2h(o1));
    const int u = u0 + wid * 8 + r;
    if (half == 0 && u < NUM_USER) {
      const float inv = 1.0f / fmaxf((float)cnt[r], 1.f);
      ((float2*)out0)[(size_t)u * 32 + c] =
          make_float2(__low2float(t0) * inv, __high2float(t0) * inv);
      ((float2*)out1)[(size_t)u * 32 + c] =
          make_float2(__low2float(t1) * inv, __high2float(t1) * inv);
    }
  }
}

// ---------------------------------------------------------------------------
// Tier-1: one-level partition + cvt (proven R16).
// ---------------------------------------------------------------------------
__global__ void k_part2cvt(const void* eu_p, const void* ei_p,
                           int* gcur_i, unsigned int* __restrict__ pairs_i,
                           int* gcur_u, unsigned int* __restrict__ pairs_u,
                           const float* __restrict__ ue, unsigned* __restrict__ u32t,
                           const float* __restrict__ ie, unsigned* __restrict__ fusedt) {
  __shared__ int hist_u[NB_U], base_u[NB_U];
  __shared__ int hist_i[NB_I], base_i[NB_I];
  if (blockIdx.x >= PGRID) {
    cvt_body((blockIdx.x - PGRID) * blockDim.x + threadIdx.x,
             CVTB * blockDim.x, ue, u32t, ie, fusedt);
    return;
  }
  for (int t = threadIdx.x; t < NB_U; t += blockDim.x) hist_u[t] = 0;
  for (int t = threadIdx.x; t < NB_I; t += blockDim.x) hist_i[t] = 0;
  __syncthreads();
  const int is64 = detect64(eu_p, ei_p);
  const int ch = NUM_EDGES / PGRID;
  const int lo = blockIdx.x * ch, hiE = lo + ch;
  for (int e = lo + threadIdx.x; e < hiE; e += blockDim.x) {
    atomicAdd(&hist_u[idx_at(eu_p, e, is64) >> 5], 1);
    atomicAdd(&hist_i[idx_at(ei_p, e, is64) >> 5], 1);
  }
  __syncthreads();
  for (int t = threadIdx.x; t < NB_U; t += blockDim.x) {
    const int h = hist_u[t];
    base_u[t] = h ? t * CAP_U + atomicAdd(&gcur_u[t], h) : 0;
    hist_u[t] = 0;
  }
  for (int t = threadIdx.x; t < NB_I; t += blockDim.x) {
    const int h = hist_i[t];
    base_i[t] = h ? t * CAP_I + atomicAdd(&gcur_i[t], h) : 0;
    hist_i[t] = 0;
  }
  __syncthreads();
  for (int e = lo + threadIdx.x; e < hiE; e += blockDim.x) {
    const int eu = idx_at(eu_p, e, is64);
    const int ei = idx_at(ei_p, e, is64);
    const int bi = ei >> 5;
    const int pi = base_i[bi] + atomicAdd(&hist_i[bi], 1);
    if (pi < (bi + 1) * CAP_I)
      pairs_i[pi] = ((unsigned)(ei & 31) << 17) | (unsigned)eu;
    const int bu = eu >> 5;
    const int pu = base_u[bu] + atomicAdd(&hist_u[bu], 1);
    if (pu < (bu + 1) * CAP_U)
      pairs_u[pu] = ((unsigned)(eu & 31) << 17) | (unsigned)ei;
  }
}

// ---------------------------------------------------------------------------
// Round-0 atomic fallback (tiny ws).
// ---------------------------------------------------------------------------
__global__ void k_scatter1(const float* __restrict__ user_emb,
                           const float* __restrict__ item_emb,
                           const void* eu_p, const void* ei_p,
                           float* out0, float* item_sum,
                           float* cnt_user, float* cnt_item) {
  const int is64 = detect64(eu_p, ei_p);
  const int lane = threadIdx.x & (DIM - 1);
  const int sub  = threadIdx.x >> 6;
  const int epb  = blockDim.x >> 6;
  for (int e = blockIdx.x * epb + sub; e < NUM_EDGES; e += gridDim.x * epb) {
    const int eu = idx_at(eu_p, e, is64);
    const int ei = idx_at(ei_p, e, is64);
    atomicAdd(&out0[eu * DIM + lane], item_emb[ei * DIM + lane]);
    atomicAdd(&item_sum[ei * DIM + lane], user_emb[eu * DIM + lane]);
    if (lane == 0) {
      atomicAdd(&cnt_user[eu], 1.0f);
      atomicAdd(&cnt_item[ei], 1.0f);
    }
  }
}

__global__ void k_div_item(float* item_sum, const float* __restrict__ cnt_item) {
  const int n = NUM_ITEM * DIM;
  for (int t = blockIdx.x * blockDim.x + threadIdx.x; t < n;
       t += gridDim.x * blockDim.x)
    item_sum[t] /= fmaxf(cnt_item[t >> 6], 1.0f);
}

__global__ void k_scatter2(const float* __restrict__ item_agg,
                           const void* eu_p, const void* ei_p, float* out1) {
  const int is64 = detect64(eu_p, ei_p);
  const int lane = threadIdx.x & (DIM - 1);
  const int sub  = threadIdx.x >> 6;
  const int epb  = blockDim.x >> 6;
  for (int e = blockIdx.x * epb + sub; e < NUM_EDGES; e += gridDim.x * epb) {
    const int eu = idx_at(eu_p, e, is64);
    const int ei = idx_at(ei_p, e, is64);
    atomicAdd(&out1[eu * DIM + lane], item_agg[ei * DIM + lane]);
  }
}

__global__ void k_finalize(float* out0, float* out1,
                           const float* __restrict__ cnt_user) {
  const int n = NUM_USER * DIM;
  for (int t = blockIdx.x * blockDim.x + threadIdx.x; t < n;
       t += gridDim.x * blockDim.x) {
    const float c = fmaxf(cnt_user[t >> 6], 1.0f);
    out0[t] /= c;
    out1[t] /= c;
  }
}

// ---------------------------------------------------------------------------
extern "C" void kernel_launch(void* const* d_in, const int* in_sizes, int n_in,
                              void* d_out, int out_size, void* d_ws, size_t ws_size,
                              hipStream_t stream) {
  const float* user_emb = (const float*)d_in[0];
  const float* item_emb = (const float*)d_in[1];
  const void*  eu_p     = d_in[2];
  const void*  ei_p     = d_in[3];

  float* out0 = (float*)d_out;
  float* out1 = out0 + (size_t)NUM_USER * DIM;

  int* wsi = (int*)d_ws;
  float* wsf = (float*)d_ws;

  // --- Tier 0: two-level partition layout (u32 units), ~82.9 MB (proven R17/R21) ---
  const size_t t0_coarse_u = 0;
  const size_t t0_coarse_i = t0_coarse_u + (size_t)NG * GCAP;
  const size_t t0_pairs_u  = t0_coarse_i + (size_t)NG * GCAP;
  const size_t t0_pairs_i  = t0_pairs_u + (size_t)NB_U * CAP_U;
  const size_t t0_user32   = t0_pairs_i + (size_t)NB_I * CAP_I;
  const size_t t0_fused    = t0_user32 + (size_t)NUM_USER * 32;
  const size_t t0_gccur    = t0_fused + (size_t)NUM_ITEM * 64;
  const size_t t0_gcnt_u   = t0_gccur + 2 * NG;
  const size_t t0_gcnt_i   = t0_gcnt_u + NB_U;
  const size_t need_t0     = (t0_gcnt_i + NB_I) * 4;

  // --- Tier 1: one-level static layout, 56.0 MB (proven R13-R16) ---
  const size_t s_pairs_u = 0;
  const size_t s_pairs_i = s_pairs_u + (size_t)NB_U * CAP_U;
  const size_t s_user32  = s_pairs_i + (size_t)NB_I * CAP_I;
  const size_t s_fused   = s_user32 + (size_t)NUM_USER * 32;
  const size_t s_gcur_u  = s_fused + (size_t)NUM_ITEM * 64;
  const size_t s_gcur_i  = s_gcur_u + NB_U;
  const size_t need_t1   = (s_gcur_i + NB_I) * 4;

  if (ws_size >= need_t0) {
    unsigned* coarse_u = (unsigned*)(wsi + t0_coarse_u);
    unsigned* coarse_i = (unsigned*)(wsi + t0_coarse_i);
    unsigned* pairs_u  = (unsigned*)(wsi + t0_pairs_u);
    unsigned* pairs_i  = (unsigned*)(wsi + t0_pairs_i);
    unsigned* user32   = (unsigned*)(wsi + t0_user32);
    unsigned* fused    = (unsigned*)(wsi + t0_fused);
    int* gccur_u = wsi + t0_gccur;
    int* gccur_i = gccur_u + NG;
    int* gcnt_u  = wsi + t0_gcnt_u;
    int* gcnt_i  = wsi + t0_gcnt_i;

    hipMemsetAsync(gccur_u, 0, (size_t)(2 * NG) * 4, stream);
    k_passA<<<PGRID + CVTB, 1024, 0, stream>>>(eu_p, ei_p, gccur_u, gccur_i,
                                               coarse_u, coarse_i,
                                               user_emb, user32, item_emb, fused);
    k_passB<<<2 * NG, 1024, 0, stream>>>(coarse_u, coarse_i, gccur_u, gccur_i,
                                         pairs_u, pairs_i, gcnt_u, gcnt_i);
    k_agg_item<<<NB_I, 256, 0, stream>>>(user32, pairs_i, gcnt_i, fused);
    k_agg_user<<<NB_U, 256, 0, stream>>>(fused, pairs_u, gcnt_u, out0, out1);
  } else if (ws_size >= need_t1) {
    unsigned* pairs_u = (unsigned*)(wsi + s_pairs_u);
    unsigned* pairs_i = (unsigned*)(wsi + s_pairs_i);
    unsigned* user32  = (unsigned*)(wsi + s_user32);
    unsigned* fused   = (unsigned*)(wsi + s_fused);
    int* gcur_u = wsi + s_gcur_u;
    int* gcur_i = wsi + s_gcur_i;

    hipMemsetAsync(gcur_u, 0, (size_t)(NB_U + NB_I) * 4, stream);
    k_part2cvt<<<PGRID + CVTB, 1024, 0, stream>>>(eu_p, ei_p, gcur_i, pairs_i,
                                                  gcur_u, pairs_u,
                                                  user_emb, user32,
                                                  item_emb, fused);
    k_agg_item<<<NB_I, 256, 0, stream>>>(user32, pairs_i, gcur_i, fused);
    k_agg_user<<<NB_U, 256, 0, stream>>>(fused, pairs_u, gcur_u, out0, out1);
  } else {
    float* item_sum = wsf;
    float* cnt_user = wsf + (size_t)NUM_ITEM * DIM;
    float* cnt_item = cnt_user + NUM_USER;
    const size_t used = ((size_t)NUM_ITEM * DIM + NUM_USER + NUM_ITEM) * 4;

    hipMemsetAsync(d_out, 0, (size_t)out_size * sizeof(float), stream);
    hipMemsetAsync(d_ws, 0, used, stream);
    k_scatter1<<<4096, 256, 0, stream>>>(user_emb, item_emb, eu_p, ei_p,
                                         out0, item_sum, cnt_user, cnt_item);
    k_div_item<<<2048, 256, 0, stream>>>(item_sum, cnt_item);
    k_scatter2<<<4096, 256, 0, stream>>>(item_sum, eu_p, ei_p, out1);
    k_finalize<<<2048, 256, 0, stream>>>(out0, out1, cnt_user);
  }
}